// Round 3
// baseline (69.898 us; speedup 1.0000x reference)
//
#include <hip/hip_runtime.h>
#include <math.h>

// Problem constants (from setup_inputs)
#define BB 8
#define HW 4096
#define LTXT 8192
#define GG 4096
#define DD 256

// Worker grid: 2144 blocks x 256 threads
//   [0,512)     vision chains:  b = id/64,  chunk = id%64  (64 rows/block, thread = 1/4 row)
//   [512,1536)  text chains:    b = (id-512)/128, chunk = %128
//   [1536,2048) genomic chains: b = (id-1536)/64, chunk = %64
//   [2048,2112) vision audit (64 blocks)
//   [2112,2144) text audit (32 blocks)
//
// ws: floats [0,2048) vision chunk products, [2048,6144) text, [6144,8192) genomic
//     doubles @byte 65536: [0,64) vision-audit partials, [64,96) text-audit partials

struct QF { float w, x, y, z; };

__device__ inline QF qmulf(const QF a, const QF b) {
    QF r;
    r.w = fmaf(a.w, b.w, -fmaf(a.x, b.x, fmaf(a.y, b.y, a.z * b.z)));
    r.x = fmaf(a.w, b.x, fmaf(a.x, b.w, fmaf(a.y, b.z, -(a.z * b.y))));
    r.y = fmaf(a.w, b.y, fmaf(a.y, b.w, fmaf(a.z, b.x, -(a.x * b.z))));
    r.z = fmaf(a.w, b.z, fmaf(a.x, b.y, fmaf(a.z, b.w, -(a.y * b.x))));
    return r;
}

// Ordered (non-commutative) 64-lane butterfly: lower lane's product on the left.
__device__ inline QF wave_ordered_prod(QF p, int lane) {
    #pragma unroll
    for (int s = 1; s < 64; s <<= 1) {
        QF o;
        o.w = __shfl_xor(p.w, s, 64);
        o.x = __shfl_xor(p.x, s, 64);
        o.y = __shfl_xor(p.y, s, 64);
        o.z = __shfl_xor(p.z, s, 64);
        const bool hi = (lane & s) != 0;
        QF a = hi ? o : p;
        QF b = hi ? p : o;
        p = qmulf(a, b);
    }
    return p;
}

template<int K>
__device__ void chain_block(const float* __restrict__ X, const float* __restrict__ W,
                            const float* __restrict__ bias, int rowBase,
                            float* __restrict__ out4, float* sprod)
{
    const int t = threadIdx.x;
    const int rl = t >> 2;          // row within chunk (0..63)
    const int quarter = t & 3;      // 16-quat segment of the row
    const int r = rowBase + rl;
    float xv[K];
    #pragma unroll
    for (int k = 0; k < K; ++k) xv[k] = X[(size_t)r * K + k];

    const int i0 = quarter * 16;
    QF p = {1.0f, 0.0f, 0.0f, 0.0f};

    #pragma unroll
    for (int g = 0; g < 2; ++g) {
        QF pg = {1.0f, 0.0f, 0.0f, 0.0f};
        float s = 1.0f;
        #pragma unroll
        for (int ii = 0; ii < 8; ++ii) {
            const int i = i0 + g * 8 + ii;
            const float4 b4 = *(const float4*)(bias + 4 * i);
            float l0 = b4.x, l1 = b4.y, l2 = b4.z, l3 = b4.w;
            #pragma unroll
            for (int k = 0; k < K; ++k) {
                const float4 w4 = *(const float4*)(W + k * DD + 4 * i);
                l0 = fmaf(xv[k], w4.x, l0);
                l1 = fmaf(xv[k], w4.y, l1);
                l2 = fmaf(xv[k], w4.z, l2);
                l3 = fmaf(xv[k], w4.w, l3);
            }
            // defer the normalize: multiply raw quat, accumulate scale (n_f32 + 1e-8f)
            const float n = sqrtf(fmaf(l0, l0, fmaf(l1, l1, fmaf(l2, l2, l3 * l3))));
            s *= (n + 1e-8f);
            QF q = { l0, l1, l2, l3 };
            pg = qmulf(pg, q);
        }
        const float inv = 1.0f / s;          // one precise divide per 8 quats
        pg.w *= inv; pg.x *= inv; pg.y *= inv; pg.z *= inv;
        p = qmulf(p, pg);
    }

    const int lane = t & 63;
    p = wave_ordered_prod(p, lane);

    const int w = t >> 6;
    if (lane == 0) { sprod[w*4+0] = p.w; sprod[w*4+1] = p.x; sprod[w*4+2] = p.y; sprod[w*4+3] = p.z; }
    __syncthreads();
    if (t == 0) {
        QF pp = { sprod[0], sprod[1], sprod[2], sprod[3] };
        #pragma unroll
        for (int wv = 1; wv < 4; ++wv) {
            QF o = { sprod[wv*4+0], sprod[wv*4+1], sprod[wv*4+2], sprod[wv*4+3] };
            pp = qmulf(pp, o);
        }
        float4 outv = { pp.w, pp.x, pp.y, pp.z };
        *(float4*)out4 = outv;
    }
}

__global__ __launch_bounds__(256) void worker_kernel(
    const float* __restrict__ vis, const float* __restrict__ txt, const float* __restrict__ gen,
    const float* __restrict__ Wv, const float* __restrict__ bv,
    const float* __restrict__ Wt, const float* __restrict__ bt,
    const float* __restrict__ Wg, const float* __restrict__ bg,
    float* __restrict__ wsf, double* __restrict__ dws)
{
    __shared__ double sred[256];
    float* sprod = (float*)sred;

    const int t  = threadIdx.x;
    const int id = blockIdx.x;

    if (id < 512) {
        const int b = id >> 6, chunk = id & 63;
        chain_block<3>(vis + (size_t)b * HW * 3, Wv, bv, chunk * 64,
                       wsf + (size_t)id * 4, sprod);
    } else if (id < 1536) {
        const int i2 = id - 512;
        const int b = i2 >> 7, chunk = i2 & 127;
        chain_block<1>(txt + (size_t)b * LTXT, Wt, bt, chunk * 64,
                       wsf + 2048 + (size_t)i2 * 4, sprod);
    } else if (id < 2048) {
        const int i2 = id - 1536;
        const int b = i2 >> 6, chunk = i2 & 63;
        chain_block<4>(gen + (size_t)b * GG * 4, Wg, bg, chunk * 64,
                       wsf + 6144 + (size_t)i2 * 4, sprod);
    } else if (id < 2112) {
        // ---------------- vision audit: thread = (row-of-64, i-quarter) ----------------
        const int aid = id - 2048;
        const int rl = t >> 2, qq = t & 3;
        const int r = aid * 64 + rl;          // 0..4095
        float gx[8], gy[8], gz[8];
        {
            float vx[8], vy[8], vz[8];
            #pragma unroll
            for (int b = 0; b < 8; ++b) {
                const size_t base = ((size_t)b * HW + r) * 3;
                vx[b] = vis[base]; vy[b] = vis[base+1]; vz[b] = vis[base+2];
            }
            #pragma unroll
            for (int b = 0; b < 8; ++b) {
                if (b == 0)      { gx[b] = vx[1]-vx[0];  gy[b] = vy[1]-vy[0];  gz[b] = vz[1]-vz[0]; }
                else if (b == 7) { gx[b] = vx[7]-vx[6];  gy[b] = vy[7]-vy[6];  gz[b] = vz[7]-vz[6]; }
                else             { gx[b] = (vx[b+1]-vx[b-1])*0.5f; gy[b] = (vy[b+1]-vy[b-1])*0.5f; gz[b] = (vz[b+1]-vz[b-1])*0.5f; }
            }
        }
        double acc = 0.0;
        for (int ii = 0; ii < 16; ++ii) {
            const int i = qq * 16 + ii;
            const float4 a0 = *(const float4*)(Wv + 4*i);
            const float4 a1 = *(const float4*)(Wv + DD + 4*i);
            const float4 a2 = *(const float4*)(Wv + 2*DD + 4*i);
            const float wq0 = a0.x + a0.y + a0.z + a0.w;
            const float wq1 = a1.x + a1.y + a1.z + a1.w;
            const float wq2 = a2.x + a2.y + a2.z + a2.w;
            float acc8 = 0.0f;
            #pragma unroll
            for (int b = 0; b < 8; ++b)
                acc8 += fabsf(fmaf(gx[b], wq0, fmaf(gy[b], wq1, gz[b] * wq2)));
            acc += (double)acc8;
        }
        sred[t] = acc;
        __syncthreads();
        for (int off = 128; off > 0; off >>= 1) {
            if (t < off) sred[t] += sred[t + off];
            __syncthreads();
        }
        if (t == 0) dws[aid] = sred[0];
    } else {
        // ---------------- text audit (gradient factor) ----------------
        const int aid = id - 2112;
        const int l = aid * 256 + t;          // 0..8191
        float tv[8];
        #pragma unroll
        for (int b = 0; b < 8; ++b) tv[b] = txt[(size_t)b * LTXT + l];
        double acc = 0.0;
        #pragma unroll
        for (int b = 0; b < 8; ++b) {
            float gb;
            if (b == 0)      gb = tv[1] - tv[0];
            else if (b == 7) gb = tv[7] - tv[6];
            else             gb = (tv[b+1] - tv[b-1]) * 0.5f;
            acc += (double)fabsf(gb);
        }
        sred[t] = acc;
        __syncthreads();
        for (int off = 128; off > 0; off >>= 1) {
            if (t < off) sred[t] += sred[t + off];
            __syncthreads();
        }
        if (t == 0) dws[64 + aid] = sred[0];
    }
}

__global__ __launch_bounds__(256) void finalize_kernel(
    const float* __restrict__ vis, const float* __restrict__ txt, const float* __restrict__ gen,
    const float* __restrict__ Wv, const float* __restrict__ bv,
    const float* __restrict__ Wt, const float* __restrict__ bt,
    const float* __restrict__ Wg, const float* __restrict__ bg,
    const float* __restrict__ wsf, const double* __restrict__ dws,
    float* __restrict__ out)
{
    __shared__ double sphi[24];     // phi[m][b]
    __shared__ double sred[256];
    __shared__ double s_sumv, s_sumt, s_sumw;
    const int t = threadIdx.x;
    const int lane = t & 63, w = t >> 6;

    // each wave handles 6 (m,b) pairs; lane-per-chunk ordered butterfly combine
    #pragma unroll
    for (int j = 0; j < 6; ++j) {
        const int pair = w * 6 + j;          // 0..23
        const int m = pair >> 3, b = pair & 7;
        QF p;
        if (m == 1) {
            const float* base = wsf + 2048 + (size_t)b * 128 * 4;
            const float4 c0 = *(const float4*)(base + (2*lane) * 4);
            const float4 c1 = *(const float4*)(base + (2*lane+1) * 4);
            QF a = { c0.x, c0.y, c0.z, c0.w };
            QF bq = { c1.x, c1.y, c1.z, c1.w };
            p = qmulf(a, bq);
        } else {
            const float* base = wsf + ((m == 0) ? 0 : 6144) + (size_t)b * 64 * 4;
            const float4 c0 = *(const float4*)(base + lane * 4);
            p = { c0.x, c0.y, c0.z, c0.w };
        }
        p = wave_ordered_prod(p, lane);
        if (lane == 0) {
            float lat[4];
            if (m == 0) {
                const float x0 = vis[(size_t)b*HW*3], x1 = vis[(size_t)b*HW*3+1], x2 = vis[(size_t)b*HW*3+2];
                #pragma unroll
                for (int c = 0; c < 4; ++c)
                    lat[c] = fmaf(x0, Wv[c], fmaf(x1, Wv[DD+c], fmaf(x2, Wv[2*DD+c], bv[c])));
            } else if (m == 1) {
                const float x0 = txt[(size_t)b*LTXT];
                #pragma unroll
                for (int c = 0; c < 4; ++c) lat[c] = fmaf(x0, Wt[c], bt[c]);
            } else {
                const float x0 = gen[(size_t)b*GG*4], x1 = gen[(size_t)b*GG*4+1],
                            x2 = gen[(size_t)b*GG*4+2], x3 = gen[(size_t)b*GG*4+3];
                #pragma unroll
                for (int c = 0; c < 4; ++c)
                    lat[c] = fmaf(x0, Wg[c], fmaf(x1, Wg[DD+c], fmaf(x2, Wg[2*DD+c], fmaf(x3, Wg[3*DD+c], bg[c]))));
            }
            const float n = sqrtf(fmaf(lat[0], lat[0], fmaf(lat[1], lat[1], fmaf(lat[2], lat[2], lat[3] * lat[3]))));
            const float inv = 1.0f / (n + 1e-8f);
            QF q0 = { lat[0]*inv, lat[1]*inv, lat[2]*inv, lat[3]*inv };
            p = qmulf(p, q0);
            double ww = (double)p.w;
            if (ww > 1.0) ww = 1.0;
            if (ww < -1.0) ww = -1.0;
            sphi[pair] = 2.0 * acos(ww);
        }
    }
    __syncthreads();

    // vision audit sum (64 partials)
    sred[t] = (t < 64) ? dws[t] : 0.0; __syncthreads();
    for (int off = 128; off > 0; off >>= 1) { if (t < off) sred[t] += sred[t+off]; __syncthreads(); }
    if (t == 0) s_sumv = sred[0];
    __syncthreads();

    // text audit sum (32 partials)
    sred[t] = (t < 32) ? dws[64 + t] : 0.0; __syncthreads();
    for (int off = 128; off > 0; off >>= 1) { if (t < off) sred[t] += sred[t+off]; __syncthreads(); }
    if (t == 0) s_sumt = sred[0];
    __syncthreads();

    // sum_i |wtq_i|
    double aw = 0.0;
    if (t < 64) {
        const int d0 = 4 * t;
        aw = (double)fabsf(Wt[d0] + Wt[d0+1] + Wt[d0+2] + Wt[d0+3]);
    }
    sred[t] = aw; __syncthreads();
    for (int off = 128; off > 0; off >>= 1) { if (t < off) sred[t] += sred[t+off]; __syncthreads(); }
    if (t == 0) s_sumw = sred[0];
    __syncthreads();

    if (t == 0) {
        double mv = 0.0, mt = 0.0;
        for (int b = 0; b < 8; ++b) { mv += sphi[b]; mt += sphi[8 + b]; }
        mv /= 8.0; mt /= 8.0;
        const double interf = fabs(mv - mt);
        for (int b = 0; b < 8; ++b)
            out[b] = (float)exp(-fabs(sphi[16 + b] - interf));
        out[8]  = (float)interf;
        out[9]  = (float)(s_sumv / 2097152.0);            // 8 * 4096 * 64
        out[10] = (float)(s_sumt * s_sumw / 4194304.0);   // 8 * 8192 * 64
    }
}

extern "C" void kernel_launch(void* const* d_in, const int* in_sizes, int n_in,
                              void* d_out, int out_size, void* d_ws, size_t ws_size,
                              hipStream_t stream) {
    (void)in_sizes; (void)n_in; (void)out_size; (void)ws_size;
    const float* vis = (const float*)d_in[0];
    const float* txt = (const float*)d_in[1];
    const float* gen = (const float*)d_in[2];
    const float* Wv  = (const float*)d_in[3];
    const float* bv  = (const float*)d_in[4];
    const float* Wt  = (const float*)d_in[5];
    const float* bt  = (const float*)d_in[6];
    const float* Wg  = (const float*)d_in[7];
    const float* bg  = (const float*)d_in[8];
    float*  wsf = (float*)d_ws;
    double* dws = (double*)((char*)d_ws + 65536);
    float*  out = (float*)d_out;

    hipLaunchKernelGGL(worker_kernel, dim3(2144), dim3(256), 0, stream,
                       vis, txt, gen, Wv, bv, Wt, bt, Wg, bg, wsf, dws);
    hipLaunchKernelGGL(finalize_kernel, dim3(1), dim3(256), 0, stream,
                       vis, txt, gen, Wv, bv, Wt, bt, Wg, bg, wsf, dws, out);
}

// Round 4
// 42.126 us; speedup vs baseline: 1.6593x; 1.6593x over previous
//
#include <hip/hip_runtime.h>
#include <math.h>

// Problem constants (from setup_inputs)
#define BB 8
#define HW 4096
#define LTXT 8192
#define GG 4096
#define DD 256

// Worker grid: 560 blocks x 256 threads, thread = one input row (64 quats)
//   [0,128)    vision chains:  b = id/16,        chunk = id%16
//   [128,384)  text chains:    b = (id-128)/32,  chunk = %32
//   [384,512)  genomic chains: b = (id-384)/16,  chunk = %16
//   [512,528)  vision audit (16 blocks, thread = row)
//   [528,560)  text audit (32 blocks, thread = position)
//
// ws: floats [0,512) vision chunk products, [512,1536) text, [1536,2048) genomic
//     doubles @byte 65536: [0,16) vision-audit partials, [16,48) text-audit partials

struct QF { float w, x, y, z; };

__device__ inline QF qmulf(const QF a, const QF b) {
    QF r;
    r.w = fmaf(a.w, b.w, -fmaf(a.x, b.x, fmaf(a.y, b.y, a.z * b.z)));
    r.x = fmaf(a.w, b.x, fmaf(a.x, b.w, fmaf(a.y, b.z, -(a.z * b.y))));
    r.y = fmaf(a.w, b.y, fmaf(a.y, b.w, fmaf(a.z, b.x, -(a.x * b.z))));
    r.z = fmaf(a.w, b.z, fmaf(a.x, b.y, fmaf(a.z, b.w, -(a.y * b.x))));
    return r;
}

// Ordered (non-commutative) 64-lane butterfly: lower lane's product on the left.
__device__ inline QF wave_ordered_prod(QF p, int lane) {
    #pragma unroll
    for (int s = 1; s < 64; s <<= 1) {
        QF o;
        o.w = __shfl_xor(p.w, s, 64);
        o.x = __shfl_xor(p.x, s, 64);
        o.y = __shfl_xor(p.y, s, 64);
        o.z = __shfl_xor(p.z, s, 64);
        const bool hi = (lane & s) != 0;
        QF a = hi ? o : p;
        QF b = hi ? p : o;
        p = qmulf(a, b);
    }
    return p;
}

// Thread = one row. 4 independent 16-quat sub-chains (ILP) with deferred
// normalization: multiply raw quats, accumulate s = prod(n_f32 + 1e-8f),
// one precise divide per sub-chain. Weight/bias addresses are block-uniform.
template<int K>
__device__ void chain_block(const float* __restrict__ X, const float* __restrict__ W,
                            const float* __restrict__ bias, int rowBase,
                            float* __restrict__ out4, float* sprod)
{
    const int t = threadIdx.x;
    const int r = rowBase + t;
    float xv[K];
    #pragma unroll
    for (int k = 0; k < K; ++k) xv[k] = X[(size_t)r * K + k];

    QF pg[4];
    float sg[4];
    #pragma unroll
    for (int g = 0; g < 4; ++g) { pg[g] = {1.0f, 0.0f, 0.0f, 0.0f}; sg[g] = 1.0f; }

    #pragma unroll 4
    for (int ii = 0; ii < 16; ++ii) {
        #pragma unroll
        for (int g = 0; g < 4; ++g) {
            const int i = g * 16 + ii;          // block-uniform index
            const float4 b4 = *(const float4*)(bias + 4 * i);
            float l0 = b4.x, l1 = b4.y, l2 = b4.z, l3 = b4.w;
            #pragma unroll
            for (int k = 0; k < K; ++k) {
                const float4 w4 = *(const float4*)(W + k * DD + 4 * i);
                l0 = fmaf(xv[k], w4.x, l0);
                l1 = fmaf(xv[k], w4.y, l1);
                l2 = fmaf(xv[k], w4.z, l2);
                l3 = fmaf(xv[k], w4.w, l3);
            }
            const float n = sqrtf(fmaf(l0, l0, fmaf(l1, l1, fmaf(l2, l2, l3 * l3))));
            sg[g] *= (n + 1e-8f);
            QF q = { l0, l1, l2, l3 };
            pg[g] = qmulf(pg[g], q);
        }
    }

    QF p;
    {
        const float inv0 = 1.0f / sg[0];
        p = { pg[0].w * inv0, pg[0].x * inv0, pg[0].y * inv0, pg[0].z * inv0 };
        #pragma unroll
        for (int g = 1; g < 4; ++g) {
            const float inv = 1.0f / sg[g];
            QF q = { pg[g].w * inv, pg[g].x * inv, pg[g].y * inv, pg[g].z * inv };
            p = qmulf(p, q);
        }
    }

    const int lane = t & 63;
    p = wave_ordered_prod(p, lane);

    const int w = t >> 6;
    if (lane == 0) { sprod[w*4+0] = p.w; sprod[w*4+1] = p.x; sprod[w*4+2] = p.y; sprod[w*4+3] = p.z; }
    __syncthreads();
    if (t == 0) {
        QF pp = { sprod[0], sprod[1], sprod[2], sprod[3] };
        #pragma unroll
        for (int wv = 1; wv < 4; ++wv) {
            QF o = { sprod[wv*4+0], sprod[wv*4+1], sprod[wv*4+2], sprod[wv*4+3] };
            pp = qmulf(pp, o);
        }
        float4 outv = { pp.w, pp.x, pp.y, pp.z };
        *(float4*)out4 = outv;
    }
}

__global__ __launch_bounds__(256) void worker_kernel(
    const float* __restrict__ vis, const float* __restrict__ txt, const float* __restrict__ gen,
    const float* __restrict__ Wv, const float* __restrict__ bv,
    const float* __restrict__ Wt, const float* __restrict__ bt,
    const float* __restrict__ Wg, const float* __restrict__ bg,
    float* __restrict__ wsf, double* __restrict__ dws)
{
    __shared__ double sred[256];
    float* sprod = (float*)sred;

    const int t  = threadIdx.x;
    const int id = blockIdx.x;

    if (id < 128) {
        const int b = id >> 4, chunk = id & 15;
        chain_block<3>(vis + (size_t)b * HW * 3, Wv, bv, chunk * 256,
                       wsf + (size_t)id * 4, sprod);
    } else if (id < 384) {
        const int i2 = id - 128;
        const int b = i2 >> 5, chunk = i2 & 31;
        chain_block<1>(txt + (size_t)b * LTXT, Wt, bt, chunk * 256,
                       wsf + 512 + (size_t)i2 * 4, sprod);
    } else if (id < 512) {
        const int i2 = id - 384;
        const int b = i2 >> 4, chunk = i2 & 15;
        chain_block<4>(gen + (size_t)b * GG * 4, Wg, bg, chunk * 256,
                       wsf + 1536 + (size_t)i2 * 4, sprod);
    } else if (id < 528) {
        // ---------------- vision audit: thread = row ----------------
        const int aid = id - 512;
        const int r = aid * 256 + t;          // 0..4095
        float gx[8], gy[8], gz[8];
        {
            float vx[8], vy[8], vz[8];
            #pragma unroll
            for (int b = 0; b < 8; ++b) {
                const size_t base = ((size_t)b * HW + r) * 3;
                vx[b] = vis[base]; vy[b] = vis[base+1]; vz[b] = vis[base+2];
            }
            #pragma unroll
            for (int b = 0; b < 8; ++b) {
                if (b == 0)      { gx[b] = vx[1]-vx[0];  gy[b] = vy[1]-vy[0];  gz[b] = vz[1]-vz[0]; }
                else if (b == 7) { gx[b] = vx[7]-vx[6];  gy[b] = vy[7]-vy[6];  gz[b] = vz[7]-vz[6]; }
                else             { gx[b] = (vx[b+1]-vx[b-1])*0.5f; gy[b] = (vy[b+1]-vy[b-1])*0.5f; gz[b] = (vz[b+1]-vz[b-1])*0.5f; }
            }
        }
        double acc = 0.0;
        #pragma unroll 4
        for (int i = 0; i < 64; ++i) {
            const float4 a0 = *(const float4*)(Wv + 4*i);
            const float4 a1 = *(const float4*)(Wv + DD + 4*i);
            const float4 a2 = *(const float4*)(Wv + 2*DD + 4*i);
            const float wq0 = a0.x + a0.y + a0.z + a0.w;
            const float wq1 = a1.x + a1.y + a1.z + a1.w;
            const float wq2 = a2.x + a2.y + a2.z + a2.w;
            float acc8 = 0.0f;
            #pragma unroll
            for (int b = 0; b < 8; ++b)
                acc8 += fabsf(fmaf(gx[b], wq0, fmaf(gy[b], wq1, gz[b] * wq2)));
            acc += (double)acc8;
        }
        sred[t] = acc;
        __syncthreads();
        for (int off = 128; off > 0; off >>= 1) {
            if (t < off) sred[t] += sred[t + off];
            __syncthreads();
        }
        if (t == 0) dws[aid] = sred[0];
    } else {
        // ---------------- text audit (gradient factor) ----------------
        const int aid = id - 528;
        const int l = aid * 256 + t;          // 0..8191
        float tv[8];
        #pragma unroll
        for (int b = 0; b < 8; ++b) tv[b] = txt[(size_t)b * LTXT + l];
        double acc = 0.0;
        #pragma unroll
        for (int b = 0; b < 8; ++b) {
            float gb;
            if (b == 0)      gb = tv[1] - tv[0];
            else if (b == 7) gb = tv[7] - tv[6];
            else             gb = (tv[b+1] - tv[b-1]) * 0.5f;
            acc += (double)fabsf(gb);
        }
        sred[t] = acc;
        __syncthreads();
        for (int off = 128; off > 0; off >>= 1) {
            if (t < off) sred[t] += sred[t + off];
            __syncthreads();
        }
        if (t == 0) dws[16 + aid] = sred[0];
    }
}

__global__ __launch_bounds__(256) void finalize_kernel(
    const float* __restrict__ vis, const float* __restrict__ txt, const float* __restrict__ gen,
    const float* __restrict__ Wv, const float* __restrict__ bv,
    const float* __restrict__ Wt, const float* __restrict__ bt,
    const float* __restrict__ Wg, const float* __restrict__ bg,
    const float* __restrict__ wsf, const double* __restrict__ dws,
    float* __restrict__ out)
{
    __shared__ double sphi[24];     // phi[m][b]
    __shared__ double sred[256];
    __shared__ double s_sumv, s_sumt, s_sumw;
    const int t = threadIdx.x;
    const int lane = t & 63, w = t >> 6;

    // each wave handles 6 (m,b) pairs; lane-per-chunk ordered butterfly combine
    #pragma unroll
    for (int j = 0; j < 6; ++j) {
        const int pair = w * 6 + j;          // 0..23
        const int m = pair >> 3, b = pair & 7;
        const int nch = (m == 1) ? 32 : 16;
        const float* base = wsf + ((m == 0) ? 0 : (m == 1) ? 512 : 1536) + (size_t)b * nch * 4;
        QF p = { 1.0f, 0.0f, 0.0f, 0.0f };
        if (lane < nch) {
            const float4 c0 = *(const float4*)(base + lane * 4);
            p = { c0.x, c0.y, c0.z, c0.w };
        }
        p = wave_ordered_prod(p, lane);
        if (lane == 0) {
            float lat[4];
            if (m == 0) {
                const float x0 = vis[(size_t)b*HW*3], x1 = vis[(size_t)b*HW*3+1], x2 = vis[(size_t)b*HW*3+2];
                #pragma unroll
                for (int c = 0; c < 4; ++c)
                    lat[c] = fmaf(x0, Wv[c], fmaf(x1, Wv[DD+c], fmaf(x2, Wv[2*DD+c], bv[c])));
            } else if (m == 1) {
                const float x0 = txt[(size_t)b*LTXT];
                #pragma unroll
                for (int c = 0; c < 4; ++c) lat[c] = fmaf(x0, Wt[c], bt[c]);
            } else {
                const float x0 = gen[(size_t)b*GG*4], x1 = gen[(size_t)b*GG*4+1],
                            x2 = gen[(size_t)b*GG*4+2], x3 = gen[(size_t)b*GG*4+3];
                #pragma unroll
                for (int c = 0; c < 4; ++c)
                    lat[c] = fmaf(x0, Wg[c], fmaf(x1, Wg[DD+c], fmaf(x2, Wg[2*DD+c], fmaf(x3, Wg[3*DD+c], bg[c]))));
            }
            const float n = sqrtf(fmaf(lat[0], lat[0], fmaf(lat[1], lat[1], fmaf(lat[2], lat[2], lat[3] * lat[3]))));
            const float inv = 1.0f / (n + 1e-8f);
            QF q0 = { lat[0]*inv, lat[1]*inv, lat[2]*inv, lat[3]*inv };
            p = qmulf(p, q0);
            double ww = (double)p.w;
            if (ww > 1.0) ww = 1.0;
            if (ww < -1.0) ww = -1.0;
            sphi[pair] = 2.0 * acos(ww);
        }
    }
    __syncthreads();

    // vision audit sum (16 partials)
    sred[t] = (t < 16) ? dws[t] : 0.0; __syncthreads();
    for (int off = 128; off > 0; off >>= 1) { if (t < off) sred[t] += sred[t+off]; __syncthreads(); }
    if (t == 0) s_sumv = sred[0];
    __syncthreads();

    // text audit sum (32 partials)
    sred[t] = (t < 32) ? dws[16 + t] : 0.0; __syncthreads();
    for (int off = 128; off > 0; off >>= 1) { if (t < off) sred[t] += sred[t+off]; __syncthreads(); }
    if (t == 0) s_sumt = sred[0];
    __syncthreads();

    // sum_i |wtq_i|
    double aw = 0.0;
    if (t < 64) {
        const int d0 = 4 * t;
        aw = (double)fabsf(Wt[d0] + Wt[d0+1] + Wt[d0+2] + Wt[d0+3]);
    }
    sred[t] = aw; __syncthreads();
    for (int off = 128; off > 0; off >>= 1) { if (t < off) sred[t] += sred[t+off]; __syncthreads(); }
    if (t == 0) s_sumw = sred[0];
    __syncthreads();

    if (t == 0) {
        double mv = 0.0, mt = 0.0;
        for (int b = 0; b < 8; ++b) { mv += sphi[b]; mt += sphi[8 + b]; }
        mv /= 8.0; mt /= 8.0;
        const double interf = fabs(mv - mt);
        for (int b = 0; b < 8; ++b)
            out[b] = (float)exp(-fabs(sphi[16 + b] - interf));
        out[8]  = (float)interf;
        out[9]  = (float)(s_sumv / 2097152.0);            // 8 * 4096 * 64
        out[10] = (float)(s_sumt * s_sumw / 4194304.0);   // 8 * 8192 * 64
    }
}

extern "C" void kernel_launch(void* const* d_in, const int* in_sizes, int n_in,
                              void* d_out, int out_size, void* d_ws, size_t ws_size,
                              hipStream_t stream) {
    (void)in_sizes; (void)n_in; (void)out_size; (void)ws_size;
    const float* vis = (const float*)d_in[0];
    const float* txt = (const float*)d_in[1];
    const float* gen = (const float*)d_in[2];
    const float* Wv  = (const float*)d_in[3];
    const float* bv  = (const float*)d_in[4];
    const float* Wt  = (const float*)d_in[5];
    const float* bt  = (const float*)d_in[6];
    const float* Wg  = (const float*)d_in[7];
    const float* bg  = (const float*)d_in[8];
    float*  wsf = (float*)d_ws;
    double* dws = (double*)((char*)d_ws + 65536);
    float*  out = (float*)d_out;

    hipLaunchKernelGGL(worker_kernel, dim3(560), dim3(256), 0, stream,
                       vis, txt, gen, Wv, bv, Wt, bt, Wg, bg, wsf, dws);
    hipLaunchKernelGGL(finalize_kernel, dim3(1), dim3(256), 0, stream,
                       vis, txt, gen, Wv, bv, Wt, bt, Wg, bg, wsf, dws, out);
}

// Round 5
// 35.312 us; speedup vs baseline: 1.9794x; 1.1930x over previous
//
#include <hip/hip_runtime.h>
#include <math.h>

// Problem constants (from setup_inputs)
#define BB 8
#define HW 4096
#define LTXT 8192
#define GG 4096
#define DD 256

// Worker grid: 560 blocks x 256 threads, thread = one input row (64 quats)
//   [0,128)    vision chains:  b = id/16,        chunk = id%16
//   [128,384)  text chains:    b = (id-128)/32,  chunk = %32
//   [384,512)  genomic chains: b = (id-384)/16,  chunk = %16
//   [512,528)  vision audit (16 blocks, thread = row)
//   [528,560)  text audit (32 blocks, thread = position)
//
// ws: floats [0,512) vision chunk products, [512,1536) text, [1536,2048) genomic
//     doubles @byte 65536: [0,16) vision-audit partials, [16,48) text-audit partials

struct QF { float w, x, y, z; };

__device__ __forceinline__ QF qmulf(const QF a, const QF b) {
    QF r;
    r.w = fmaf(a.w, b.w, -fmaf(a.x, b.x, fmaf(a.y, b.y, a.z * b.z)));
    r.x = fmaf(a.w, b.x, fmaf(a.x, b.w, fmaf(a.y, b.z, -(a.z * b.y))));
    r.y = fmaf(a.w, b.y, fmaf(a.y, b.w, fmaf(a.z, b.x, -(a.x * b.z))));
    r.z = fmaf(a.w, b.z, fmaf(a.x, b.y, fmaf(a.z, b.w, -(a.y * b.x))));
    return r;
}

// Ordered (non-commutative) 64-lane butterfly: lower lane's product on the left.
__device__ __forceinline__ QF wave_ordered_prod(QF p, int lane) {
    #pragma unroll
    for (int s = 1; s < 64; s <<= 1) {
        QF o;
        o.w = __shfl_xor(p.w, s, 64);
        o.x = __shfl_xor(p.x, s, 64);
        o.y = __shfl_xor(p.y, s, 64);
        o.z = __shfl_xor(p.z, s, 64);
        const bool hi = (lane & s) != 0;
        QF a = hi ? o : p;
        QF b = hi ? p : o;
        p = qmulf(a, b);
    }
    return p;
}

// Thread = one row. Software-pipelined double-buffered weight staging:
// batch of BQ quats lives in a register array; next batch's loads issue
// before current batch's compute, hiding L1 latency. Deferred normalization:
// raw quat product + s = prod(n_f32 + 1e-8f), one precise divide per batch.
template<int K, int BQ>
__device__ __forceinline__ void chain_block(
    const float* __restrict__ X, const float* __restrict__ W,
    const float* __restrict__ bias, int rowBase,
    float* __restrict__ out4, float* sprod)
{
    constexpr int V = K + 1;          // float4 vectors per quat (bias + K weights)
    constexpr int NB = 64 / BQ;       // batches per row
    const int t = threadIdx.x;
    const int r = rowBase + t;
    float xv[K];
    #pragma unroll
    for (int k = 0; k < K; ++k) xv[k] = X[(size_t)r * K + k];

    float4 A[BQ * V], Bb[BQ * V];
    QF p = {1.0f, 0.0f, 0.0f, 0.0f};

    auto LOADB = [&](float4* dst, int bidx) {
        const float* bb = bias + 4 * (bidx * BQ);
        const float* wb = W + 4 * (bidx * BQ);
        #pragma unroll
        for (int j = 0; j < BQ; ++j) {
            dst[j * V + 0] = *(const float4*)(bb + 4 * j);
            #pragma unroll
            for (int k = 0; k < K; ++k)
                dst[j * V + 1 + k] = *(const float4*)(wb + k * DD + 4 * j);
        }
    };

    auto COMPUTE = [&](const float4* src, int bidx) {
        QF pb; float sb;
        #pragma unroll
        for (int j = 0; j < BQ; ++j) {
            const float4 b4 = src[j * V + 0];
            float l0 = b4.x, l1 = b4.y, l2 = b4.z, l3 = b4.w;
            #pragma unroll
            for (int k = 0; k < K; ++k) {
                const float4 w4 = src[j * V + 1 + k];
                l0 = fmaf(xv[k], w4.x, l0);
                l1 = fmaf(xv[k], w4.y, l1);
                l2 = fmaf(xv[k], w4.z, l2);
                l3 = fmaf(xv[k], w4.w, l3);
            }
            const float n = sqrtf(fmaf(l0, l0, fmaf(l1, l1, fmaf(l2, l2, l3 * l3))));
            QF q = { l0, l1, l2, l3 };
            if (j == 0) { pb = q; sb = n + 1e-8f; }
            else        { pb = qmulf(pb, q); sb *= (n + 1e-8f); }
        }
        const float inv = 1.0f / sb;            // one precise divide per batch
        QF pbn = { pb.w * inv, pb.x * inv, pb.y * inv, pb.z * inv };
        if (bidx == 0) p = pbn;                 // uniform branch (scalar)
        else           p = qmulf(p, pbn);
    };

    LOADB(A, 0);
    for (int gg = 0; gg < NB / 2; ++gg) {
        LOADB(Bb, 2 * gg + 1);                  // prefetch odd batch
        COMPUTE(A, 2 * gg);
        const int nb = (2 * gg + 2 < NB) ? (2 * gg + 2) : (NB - 1);
        LOADB(A, nb);                           // prefetch next even batch
        COMPUTE(Bb, 2 * gg + 1);
    }

    const int lane = t & 63;
    p = wave_ordered_prod(p, lane);

    const int w = t >> 6;
    if (lane == 0) { sprod[w*4+0] = p.w; sprod[w*4+1] = p.x; sprod[w*4+2] = p.y; sprod[w*4+3] = p.z; }
    __syncthreads();
    if (t == 0) {
        QF pp = { sprod[0], sprod[1], sprod[2], sprod[3] };
        #pragma unroll
        for (int wv = 1; wv < 4; ++wv) {
            QF o = { sprod[wv*4+0], sprod[wv*4+1], sprod[wv*4+2], sprod[wv*4+3] };
            pp = qmulf(pp, o);
        }
        float4 outv = { pp.w, pp.x, pp.y, pp.z };
        *(float4*)out4 = outv;
    }
}

__global__ __launch_bounds__(256) void worker_kernel(
    const float* __restrict__ vis, const float* __restrict__ txt, const float* __restrict__ gen,
    const float* __restrict__ Wv, const float* __restrict__ bv,
    const float* __restrict__ Wt, const float* __restrict__ bt,
    const float* __restrict__ Wg, const float* __restrict__ bg,
    float* __restrict__ wsf, double* __restrict__ dws)
{
    __shared__ double sred[256];
    float* sprod = (float*)sred;

    const int t  = threadIdx.x;
    const int id = blockIdx.x;

    if (id < 128) {
        const int b = id >> 4, chunk = id & 15;
        chain_block<3, 4>(vis + (size_t)b * HW * 3, Wv, bv, chunk * 256,
                          wsf + (size_t)id * 4, sprod);
    } else if (id < 384) {
        const int i2 = id - 128;
        const int b = i2 >> 5, chunk = i2 & 31;
        chain_block<1, 8>(txt + (size_t)b * LTXT, Wt, bt, chunk * 256,
                          wsf + 512 + (size_t)i2 * 4, sprod);
    } else if (id < 512) {
        const int i2 = id - 384;
        const int b = i2 >> 4, chunk = i2 & 15;
        chain_block<4, 2>(gen + (size_t)b * GG * 4, Wg, bg, chunk * 256,
                          wsf + 1536 + (size_t)i2 * 4, sprod);
    } else if (id < 528) {
        // ---------------- vision audit: thread = row ----------------
        const int aid = id - 512;
        const int r = aid * 256 + t;          // 0..4095
        float gx[8], gy[8], gz[8];
        {
            float vx[8], vy[8], vz[8];
            #pragma unroll
            for (int b = 0; b < 8; ++b) {
                const size_t base = ((size_t)b * HW + r) * 3;
                vx[b] = vis[base]; vy[b] = vis[base+1]; vz[b] = vis[base+2];
            }
            #pragma unroll
            for (int b = 0; b < 8; ++b) {
                if (b == 0)      { gx[b] = vx[1]-vx[0];  gy[b] = vy[1]-vy[0];  gz[b] = vz[1]-vz[0]; }
                else if (b == 7) { gx[b] = vx[7]-vx[6];  gy[b] = vy[7]-vy[6];  gz[b] = vz[7]-vz[6]; }
                else             { gx[b] = (vx[b+1]-vx[b-1])*0.5f; gy[b] = (vy[b+1]-vy[b-1])*0.5f; gz[b] = (vz[b+1]-vz[b-1])*0.5f; }
            }
        }
        double acc = 0.0;
        #pragma unroll 4
        for (int i = 0; i < 64; ++i) {
            const float4 a0 = *(const float4*)(Wv + 4*i);
            const float4 a1 = *(const float4*)(Wv + DD + 4*i);
            const float4 a2 = *(const float4*)(Wv + 2*DD + 4*i);
            const float wq0 = a0.x + a0.y + a0.z + a0.w;
            const float wq1 = a1.x + a1.y + a1.z + a1.w;
            const float wq2 = a2.x + a2.y + a2.z + a2.w;
            float acc8 = 0.0f;
            #pragma unroll
            for (int b = 0; b < 8; ++b)
                acc8 += fabsf(fmaf(gx[b], wq0, fmaf(gy[b], wq1, gz[b] * wq2)));
            acc += (double)acc8;
        }
        sred[t] = acc;
        __syncthreads();
        for (int off = 128; off > 0; off >>= 1) {
            if (t < off) sred[t] += sred[t + off];
            __syncthreads();
        }
        if (t == 0) dws[aid] = sred[0];
    } else {
        // ---------------- text audit (gradient factor) ----------------
        const int aid = id - 528;
        const int l = aid * 256 + t;          // 0..8191
        float tv[8];
        #pragma unroll
        for (int b = 0; b < 8; ++b) tv[b] = txt[(size_t)b * LTXT + l];
        double acc = 0.0;
        #pragma unroll
        for (int b = 0; b < 8; ++b) {
            float gb;
            if (b == 0)      gb = tv[1] - tv[0];
            else if (b == 7) gb = tv[7] - tv[6];
            else             gb = (tv[b+1] - tv[b-1]) * 0.5f;
            acc += (double)fabsf(gb);
        }
        sred[t] = acc;
        __syncthreads();
        for (int off = 128; off > 0; off >>= 1) {
            if (t < off) sred[t] += sred[t + off];
            __syncthreads();
        }
        if (t == 0) dws[16 + aid] = sred[0];
    }
}

__global__ __launch_bounds__(256) void finalize_kernel(
    const float* __restrict__ vis, const float* __restrict__ txt, const float* __restrict__ gen,
    const float* __restrict__ Wv, const float* __restrict__ bv,
    const float* __restrict__ Wt, const float* __restrict__ bt,
    const float* __restrict__ Wg, const float* __restrict__ bg,
    const float* __restrict__ wsf, const double* __restrict__ dws,
    float* __restrict__ out)
{
    __shared__ double sphi[24];     // phi[m][b]
    __shared__ double sred[256];
    __shared__ double s_sumv, s_sumt, s_sumw;
    const int t = threadIdx.x;
    const int lane = t & 63, w = t >> 6;

    // each wave handles 6 (m,b) pairs; lane-per-chunk ordered butterfly combine
    #pragma unroll
    for (int j = 0; j < 6; ++j) {
        const int pair = w * 6 + j;          // 0..23
        const int m = pair >> 3, b = pair & 7;
        const int nch = (m == 1) ? 32 : 16;
        const float* base = wsf + ((m == 0) ? 0 : (m == 1) ? 512 : 1536) + (size_t)b * nch * 4;
        QF p = { 1.0f, 0.0f, 0.0f, 0.0f };
        if (lane < nch) {
            const float4 c0 = *(const float4*)(base + lane * 4);
            p = { c0.x, c0.y, c0.z, c0.w };
        }
        p = wave_ordered_prod(p, lane);
        if (lane == 0) {
            float lat[4];
            if (m == 0) {
                const float x0 = vis[(size_t)b*HW*3], x1 = vis[(size_t)b*HW*3+1], x2 = vis[(size_t)b*HW*3+2];
                #pragma unroll
                for (int c = 0; c < 4; ++c)
                    lat[c] = fmaf(x0, Wv[c], fmaf(x1, Wv[DD+c], fmaf(x2, Wv[2*DD+c], bv[c])));
            } else if (m == 1) {
                const float x0 = txt[(size_t)b*LTXT];
                #pragma unroll
                for (int c = 0; c < 4; ++c) lat[c] = fmaf(x0, Wt[c], bt[c]);
            } else {
                const float x0 = gen[(size_t)b*GG*4], x1 = gen[(size_t)b*GG*4+1],
                            x2 = gen[(size_t)b*GG*4+2], x3 = gen[(size_t)b*GG*4+3];
                #pragma unroll
                for (int c = 0; c < 4; ++c)
                    lat[c] = fmaf(x0, Wg[c], fmaf(x1, Wg[DD+c], fmaf(x2, Wg[2*DD+c], fmaf(x3, Wg[3*DD+c], bg[c]))));
            }
            const float n = sqrtf(fmaf(lat[0], lat[0], fmaf(lat[1], lat[1], fmaf(lat[2], lat[2], lat[3] * lat[3]))));
            const float inv = 1.0f / (n + 1e-8f);
            QF q0 = { lat[0]*inv, lat[1]*inv, lat[2]*inv, lat[3]*inv };
            p = qmulf(p, q0);
            double ww = (double)p.w;
            if (ww > 1.0) ww = 1.0;
            if (ww < -1.0) ww = -1.0;
            sphi[pair] = 2.0 * acos(ww);
        }
    }
    __syncthreads();

    // vision audit sum (16 partials)
    sred[t] = (t < 16) ? dws[t] : 0.0; __syncthreads();
    for (int off = 128; off > 0; off >>= 1) { if (t < off) sred[t] += sred[t+off]; __syncthreads(); }
    if (t == 0) s_sumv = sred[0];
    __syncthreads();

    // text audit sum (32 partials)
    sred[t] = (t < 32) ? dws[16 + t] : 0.0; __syncthreads();
    for (int off = 128; off > 0; off >>= 1) { if (t < off) sred[t] += sred[t+off]; __syncthreads(); }
    if (t == 0) s_sumt = sred[0];
    __syncthreads();

    // sum_i |wtq_i|
    double aw = 0.0;
    if (t < 64) {
        const int d0 = 4 * t;
        aw = (double)fabsf(Wt[d0] + Wt[d0+1] + Wt[d0+2] + Wt[d0+3]);
    }
    sred[t] = aw; __syncthreads();
    for (int off = 128; off > 0; off >>= 1) { if (t < off) sred[t] += sred[t+off]; __syncthreads(); }
    if (t == 0) s_sumw = sred[0];
    __syncthreads();

    if (t == 0) {
        double mv = 0.0, mt = 0.0;
        for (int b = 0; b < 8; ++b) { mv += sphi[b]; mt += sphi[8 + b]; }
        mv /= 8.0; mt /= 8.0;
        const double interf = fabs(mv - mt);
        for (int b = 0; b < 8; ++b)
            out[b] = (float)exp(-fabs(sphi[16 + b] - interf));
        out[8]  = (float)interf;
        out[9]  = (float)(s_sumv / 2097152.0);            // 8 * 4096 * 64
        out[10] = (float)(s_sumt * s_sumw / 4194304.0);   // 8 * 8192 * 64
    }
}

extern "C" void kernel_launch(void* const* d_in, const int* in_sizes, int n_in,
                              void* d_out, int out_size, void* d_ws, size_t ws_size,
                              hipStream_t stream) {
    (void)in_sizes; (void)n_in; (void)out_size; (void)ws_size;
    const float* vis = (const float*)d_in[0];
    const float* txt = (const float*)d_in[1];
    const float* gen = (const float*)d_in[2];
    const float* Wv  = (const float*)d_in[3];
    const float* bv  = (const float*)d_in[4];
    const float* Wt  = (const float*)d_in[5];
    const float* bt  = (const float*)d_in[6];
    const float* Wg  = (const float*)d_in[7];
    const float* bg  = (const float*)d_in[8];
    float*  wsf = (float*)d_ws;
    double* dws = (double*)((char*)d_ws + 65536);
    float*  out = (float*)d_out;

    hipLaunchKernelGGL(worker_kernel, dim3(560), dim3(256), 0, stream,
                       vis, txt, gen, Wv, bv, Wt, bt, Wg, bg, wsf, dws);
    hipLaunchKernelGGL(finalize_kernel, dim3(1), dim3(256), 0, stream,
                       vis, txt, gen, Wv, bv, Wt, bt, Wg, bg, wsf, dws, out);
}